// Round 1
// baseline (6102.398 us; speedup 1.0000x reference)
//
#include <hip/hip_runtime.h>
#include <math.h>

#define V_   8
#define H_   256
#define W_   256
#define L_   32
#define HID_ 64
#define NC_  64
#define NF_  64
#define R_   1024
#define IND_ 41              // 3 + 32 + 3 + 3
#define HW_  (H_*W_)

// ---------------------------------------------------------------- P = K @ E
__global__ void k_computeP(const float* __restrict__ Km,
                           const float* __restrict__ Em,
                           float* __restrict__ Pm) {
    int t = threadIdx.x;
    if (t >= V_ * 12) return;
    int v = t / 12, e = t - v * 12, row = e >> 2, col = e & 3;
    float acc = 0.f;
    #pragma unroll
    for (int k = 0; k < 3; ++k)
        acc += Km[v * 9 + row * 3 + k] * Em[v * 12 + k * 4 + col];
    Pm[v * 12 + row * 4 + col] = acc;
}

// ------------------------------------------------- per-point gather + MLP
// One wave (64 lanes) per point-sample; lane = hidden channel index.
template <int S, int FS, bool FINE>
__global__ __launch_bounds__(256) void k_points(
    const float* __restrict__ ray, const float* __restrict__ Pm,
    const float* __restrict__ cam, const float* __restrict__ shp,
    const float* __restrict__ msk, const float* __restrict__ img,
    const float* __restrict__ fea,
    const float* __restrict__ W1, const float* __restrict__ b1,
    const float* __restrict__ W2, const float* __restrict__ b2,
    const float* __restrict__ Wd, const float* __restrict__ bd,
    const float* __restrict__ Wb, const float* __restrict__ bb,
    const float* __restrict__ deptharr,
    float* __restrict__ odens, float* __restrict__ orgb) {

    const int wid  = (int)((blockIdx.x * blockDim.x + threadIdx.x) >> 6);
    const int lane = threadIdx.x & 63;
    const int r = wid / S, s = wid - r * S;

    // register-cached weight columns for this lane's hidden channel
    float w1c[IND_];
    #pragma unroll
    for (int k = 0; k < IND_; ++k) w1c[k] = W1[k * HID_ + lane];
    float w2c[HID_];
    #pragma unroll
    for (int k = 0; k < HID_; ++k) w2c[k] = W2[k * HID_ + lane];
    const float b1j = b1[lane], b2j = b2[lane], wbj = Wb[lane];
    const float wd0 = Wd[lane], wd1 = Wd[HID_ + lane];
    const float bdv = bd[0], bbv = bb[0];

    const float ox = ray[r*8+0], oy = ray[r*8+1], oz = ray[r*8+2];
    const float dx = ray[r*8+3], dy = ray[r*8+4], dz = ray[r*8+5];
    const float nv = ray[r*8+6], fv = ray[r*8+7];

    float depth;
    if (FINE) depth = deptharr[wid];
    else      depth = nv + (fv - nv) * ((s + 0.5f) / (float)S);

    const float px = ox + dx*depth, py = oy + dy*depth, pz = oz + dz*depth;
    const float dn = sqrtf(dx*dx + dy*dy + dz*dz);
    const float rdx = -dx/dn, rdy = -dy/dn, rdz = -dz/dn;   // ray_dirc = -d/|d|

    float sumh = 0.f, sumq = 0.f, hullsum = 0.f;
    float logit[V_], rgbv0[V_], rgbv1[V_], rgbv2[V_];

    #pragma unroll
    for (int v = 0; v < V_; ++v) {
        const float* Pv = Pm + v * 12;
        float q0 = Pv[0]*px + Pv[1]*py + Pv[2]*pz  + Pv[3];
        float q1 = Pv[4]*px + Pv[5]*py + Pv[6]*pz  + Pv[7];
        float q2 = Pv[8]*px + Pv[9]*py + Pv[10]*pz + Pv[11];
        float inv = 1.0f / (q2 + 1e-6f);
        float u = q0 * inv, w = q1 * inv;
        // wh = source_shape[:, ::-1]  -> (W, H)
        float gx = 2.0f * (u / shp[v*2+1]) - 1.0f;
        float gy = 2.0f * (w / shp[v*2+0]) - 1.0f;
        float sx = (gx + 1.0f) * ((float)W_ * 0.5f) - 0.5f;
        float sy = (gy + 1.0f) * ((float)H_ * 0.5f) - 0.5f;
        float x0f = floorf(sx), y0f = floorf(sy);
        float fx = sx - x0f, fy = sy - y0f;

        int offp[4]; float wt[4];
        {
            float xs[2] = {x0f, x0f + 1.f}, ys[2] = {y0f, y0f + 1.f};
            float wxs[2] = {1.f - fx, fx},  wys[2] = {1.f - fy, fy};
            #pragma unroll
            for (int t = 0; t < 4; ++t) {
                float xf = xs[t & 1], yf = ys[t >> 1];
                bool val = (xf >= 0.f) && (xf <= (float)(W_-1)) &&
                           (yf >= 0.f) && (yf <= (float)(H_-1));
                int xi = (int)fminf(fmaxf(xf, 0.f), (float)(W_-1));
                int yi = (int)fminf(fmaxf(yf, 0.f), (float)(H_-1));
                offp[t] = yi * W_ + xi;
                wt[t] = wxs[t & 1] * wys[t >> 1] * (val ? 1.f : 0.f);
            }
        }
        // mask sample (all-lanes broadcast loads)
        const float* mb = msk + v * HW_;
        hullsum += wt[0]*mb[offp[0]] + wt[1]*mb[offp[1]]
                 + wt[2]*mb[offp[2]] + wt[3]*mb[offp[3]];
        // rgb sample
        float rv0 = 0.f, rv1 = 0.f, rv2 = 0.f;
        {
            const float* ib = img + (v * 3) * HW_;
            #pragma unroll
            for (int t = 0; t < 4; ++t) {
                rv0 += wt[t] * ib[offp[t]];
                rv1 += wt[t] * ib[HW_ + offp[t]];
                rv2 += wt[t] * ib[2 * HW_ + offp[t]];
            }
        }
        rgbv0[v] = rv0; rgbv1[v] = rv1; rgbv2[v] = rv2;
        // source direction
        float sdx = cam[v*3+0]-px, sdy = cam[v*3+1]-py, sdz = cam[v*3+2]-pz;
        float snv = sqrtf(sdx*sdx + sdy*sdy + sdz*sdz);
        sdx /= snv; sdy /= snv; sdz /= snv;

        // x vector distributed across lanes 0..40
        float xl = 0.f;
        if (lane < 3) {
            xl = (lane == 0) ? rv0 : ((lane == 1) ? rv1 : rv2);
        } else if (lane < 35) {
            const float* fb = fea + (size_t)(v * (2*L_) + FS + (lane - 3)) * HW_;
            xl = wt[0]*fb[offp[0]] + wt[1]*fb[offp[1]]
               + wt[2]*fb[offp[2]] + wt[3]*fb[offp[3]];
        } else if (lane == 35) xl = sdx;
        else if (lane == 36) xl = sdy;
        else if (lane == 37) xl = sdz;
        else if (lane == 38) xl = rdx;
        else if (lane == 39) xl = rdy;
        else if (lane == 40) xl = rdz;

        // h1 = relu(x @ W1 + b1)   (lane j computes channel j)
        float a1 = b1j;
        #pragma unroll
        for (int k = 0; k < IND_; ++k) a1 += __shfl(xl, k, 64) * w1c[k];
        float h1 = fmaxf(a1, 0.f);
        // h = relu(h1 @ W2 + b2)
        float a2 = b2j;
        #pragma unroll
        for (int k = 0; k < HID_; ++k) a2 += __shfl(h1, k, 64) * w2c[k];
        float h = fmaxf(a2, 0.f);

        sumh += h; sumq += h * h;
        // blend logit = h . Wb + bb  (wave allreduce)
        float tl = h * wbj;
        #pragma unroll
        for (int off = 32; off >= 1; off >>= 1) tl += __shfl_xor(tl, off, 64);
        logit[v] = tl + bbv;
    }

    // pooled -> density
    float mean = sumh * (1.0f / V_);
    float var  = sumq * (1.0f / V_) - mean * mean;
    float dt = mean * wd0 + var * wd1;
    #pragma unroll
    for (int off = 32; off >= 1; off >>= 1) dt += __shfl_xor(dt, off, 64);
    float density = dt + bdv;

    // softmax blend over views -> rgb
    float mx = logit[0];
    #pragma unroll
    for (int v = 1; v < V_; ++v) mx = fmaxf(mx, logit[v]);
    float es = 0.f, a0 = 0.f, a1c = 0.f, a2c = 0.f;
    #pragma unroll
    for (int v = 0; v < V_; ++v) {
        float e = expf(logit[v] - mx);
        es += e;
        a0 += e * rgbv0[v]; a1c += e * rgbv1[v]; a2c += e * rgbv2[v];
    }
    bool hull = hullsum > ((float)V_ - 0.001f);
    if (lane == 0) {
        float is = 1.0f / es;
        odens[wid]      = hull ? density   : 0.f;
        orgb[wid*3 + 0] = hull ? a0  * is  : 0.f;
        orgb[wid*3 + 1] = hull ? a1c * is  : 0.f;
        orgb[wid*3 + 2] = hull ? a2c * is  : 0.f;
    }
}

// ---------------------------------------- coarse composite + sample_pdf + merge
__global__ void k_comp_coarse(const float* __restrict__ ray,
                              const float* __restrict__ dens,
                              const float* __restrict__ rgb,
                              float* __restrict__ out,
                              float* __restrict__ fulld) {
    int r = blockIdx.x * blockDim.x + threadIdx.x;
    if (r >= R_) return;
    const float nv = ray[r*8+6], fv = ray[r*8+7];

    float wv[NC_];
    float T = 1.f, c0 = 0.f, c1 = 0.f, c2 = 0.f, cd = 0.f, ca = 0.f;
    for (int s = 0; s < NC_; ++s) {
        float d0 = nv + (fv - nv) * ((s + 0.5f) / NC_);
        float d1 = nv + (fv - nv) * ((s + 1.5f) / NC_);
        float delta = (s == NC_-1) ? 1e10f : (d1 - d0);
        float a = 1.f - expf(-fmaxf(dens[r*NC_+s], 0.f) * delta);
        float wi = a * T;
        wv[s] = wi;
        c0 += wi * rgb[(r*NC_+s)*3+0];
        c1 += wi * rgb[(r*NC_+s)*3+1];
        c2 += wi * rgb[(r*NC_+s)*3+2];
        cd += wi * d0; ca += wi;
        T *= (1.f - a + 1e-10f);
    }
    out[r*3+0] = c0; out[r*3+1] = c1; out[r*3+2] = c2;
    out[3072 + r] = cd;
    out[4096 + r] = ca;

    // ---- sample_pdf(mids, w[1:-1], NF) ----
    float tot = 0.f;
    for (int i = 0; i < 62; ++i) tot += wv[i+1] + 1e-5f;
    float cdf[63];
    cdf[0] = 0.f;
    float run = 0.f;
    for (int i = 0; i < 62; ++i) { run += (wv[i+1] + 1e-5f) / tot; cdf[i+1] = run; }

    float fd[NF_];
    int idx = 1;                      // searchsorted(cdf, u, 'right'), u>0 so >=1
    for (int i = 0; i < NF_; ++i) {
        float u = (i + 0.5f) / NF_;
        while (idx < 63 && cdf[idx] <= u) ++idx;
        int below = idx - 1;
        int above = (idx > 62) ? 62 : idx;
        float cA = cdf[below], cB = cdf[above];
        // mids[i] = near + (far-near)*(i+1)/NC
        float b0 = nv + (fv - nv) * ((below + 1.0f) / NC_);
        float b1 = nv + (fv - nv) * ((above + 1.0f) / NC_);
        float dnm = cB - cA;
        dnm = (dnm < 1e-5f) ? 1.f : dnm;
        float t = (u - cA) / dnm;
        fd[i] = b0 + t * (b1 - b0);
    }
    // ---- merge coarse (formula, sorted) with fd (sorted) -> full_depth ----
    float* fl = fulld + r * (NC_ + NF_);
    int a_ = 0, b_ = 0;
    for (int i = 0; i < NC_ + NF_; ++i) {
        float da = (a_ < NC_) ? nv + (fv - nv) * ((a_ + 0.5f) / NC_) : 3.0e38f;
        float db = (b_ < NF_) ? fd[b_] : 3.0e38f;
        if (da <= db) { fl[i] = da; ++a_; } else { fl[i] = db; ++b_; }
    }
}

// ---------------------------------------------------------- fine composite
__global__ void k_comp_fine(const float* __restrict__ fulld,
                            const float* __restrict__ dens,
                            const float* __restrict__ rgb,
                            float* __restrict__ out) {
    int r = blockIdx.x * blockDim.x + threadIdx.x;
    if (r >= R_) return;
    const int S = NC_ + NF_;
    const float* fl = fulld + r * S;
    float T = 1.f, c0 = 0.f, c1 = 0.f, c2 = 0.f, cd = 0.f, ca = 0.f;
    for (int s = 0; s < S; ++s) {
        float d0 = fl[s];
        float delta = (s == S-1) ? 1e10f : (fl[s+1] - d0);
        float a = 1.f - expf(-fmaxf(dens[r*S+s], 0.f) * delta);
        float wi = a * T;
        c0 += wi * rgb[(r*S+s)*3+0];
        c1 += wi * rgb[(r*S+s)*3+1];
        c2 += wi * rgb[(r*S+s)*3+2];
        cd += wi * d0; ca += wi;
        T *= (1.f - a + 1e-10f);
    }
    out[5120 + r*3+0] = c0; out[5120 + r*3+1] = c1; out[5120 + r*3+2] = c2;
    out[8192 + r] = cd;
    out[9216 + r] = ca;
}

// ------------------------------------------------------------------ launch
extern "C" void kernel_launch(void* const* d_in, const int* in_sizes, int n_in,
                              void* d_out, int out_size, void* d_ws, size_t ws_size,
                              hipStream_t stream) {
    const float* ray = (const float*)d_in[0];
    const float* Kin = (const float*)d_in[1];
    const float* Ein = (const float*)d_in[2];
    const float* cam = (const float*)d_in[3];
    const float* shp = (const float*)d_in[4];
    const float* msk = (const float*)d_in[5];
    const float* img = (const float*)d_in[6];
    const float* fea = (const float*)d_in[7];
    const float* cw[8]; for (int i = 0; i < 8; ++i) cw[i] = (const float*)d_in[8+i];
    const float* fw[8]; for (int i = 0; i < 8; ++i) fw[i] = (const float*)d_in[16+i];

    float* ws    = (float*)d_ws;
    float* Pm    = ws;                       // 96
    float* cdens = Pm + 96;                  // R*NC
    float* crgb  = cdens + R_ * NC_;         // R*NC*3
    float* fulld = crgb + R_ * NC_ * 3;      // R*128
    float* fdens = fulld + R_ * (NC_+NF_);   // R*128
    float* frgb  = fdens + R_ * (NC_+NF_);   // R*128*3
    float* outp  = (float*)d_out;

    k_computeP<<<1, 96, 0, stream>>>(Kin, Ein, Pm);

    k_points<NC_, 0, false><<<R_ * NC_ / 4, 256, 0, stream>>>(
        ray, Pm, cam, shp, msk, img, fea,
        cw[0], cw[1], cw[2], cw[3], cw[4], cw[5], cw[6], cw[7],
        nullptr, cdens, crgb);

    k_comp_coarse<<<R_ / 256, 256, 0, stream>>>(ray, cdens, crgb, outp, fulld);

    k_points<NC_ + NF_, L_, true><<<R_ * (NC_+NF_) / 4, 256, 0, stream>>>(
        ray, Pm, cam, shp, msk, img, fea,
        fw[0], fw[1], fw[2], fw[3], fw[4], fw[5], fw[6], fw[7],
        fulld, fdens, frgb);

    k_comp_fine<<<R_ / 256, 256, 0, stream>>>(fulld, fdens, frgb, outp);
}